// Round 16
// baseline (291.240 us; speedup 1.0000x reference)
//
#include <hip/hip_runtime.h>
#include <stdint.h>

// CIN layers: Xn[b,h,d] = sum_{j,k} W[h,j,k] * X0[b,j,d] * Xi[b,k,d] + bias[h]
// y[d,h] = sum_k Xi*W (mfma_32x32x16, A rows m=b'*16+d, B cols=32h), then
// Xacc += x0[b,j,d]*y.
// R25 post-mortem: L0-K48 + setprio landed (-16us fused, 281 total, best).
// Volume-cut thesis: 5-for-5. Remaining: fused 219 + 62us prep/gap overhead.
// The 4096 X0-prep blocks + X0T/X0f round-trip (~33MB) are pure pass-through
// with ZERO cross-block reuse (each b feeds exactly one cin block).
// R26: in-kernel X0 staging. cin_fused takes raw X0g; at block start it
// (1) fills x0f LDS with the d-permutation inline (coalesced 64B-line reads)
// and (2) builds the L0 A-fragment tile X0s[4][16][56] bf16 via in-kernel
// transpose (k>=39 zeroed; 56-short rows = 112B keep b128 reads 16B-aligned;
// one-time L1-hot gather). L0 af reads LDS. Prep launch = W-only (5928 tiny
// blocks). Kills 4096 prep blocks + 33MB round-trip; costs ~5us one-time
// staging + LDS 43.5->50.4KB (still VGPR-bound, no occupancy change).
// Everything else = R25: fused 3 layers, Xn via LDS (XROW=130), f32 x0,
// j-major, W global->reg ping-pong, setprio chains, launch_bounds(256,1).

#define NB_F0 39
#define NB_H  128
#define NB_B  4096
#define XROW 130   // padded k-row stride (shorts) for Xa/Xb
#define X0ROW 56   // padded k-row stride (shorts) for X0s (112B, 16B-aligned)

typedef float f32x4  __attribute__((ext_vector_type(4)));
typedef float f32x16 __attribute__((ext_vector_type(16)));
typedef short s16x8  __attribute__((ext_vector_type(8)));

template <int N> struct IC { static constexpr int value = N; };

__device__ __forceinline__ unsigned short rne_bf16(float f) {
  union { float f; unsigned u; } v; v.f = f;
  return (unsigned short)((v.u + 0x7fffu + ((v.u >> 16) & 1u)) >> 16);
}

// W-only prep (one launch): W f32 [128][39*Fi] -> Wf bf16 fragment-linear:
//   Wf[(((j*4+t)*KC16+c)*64+lane)*8+i] = W[h=t*32+(lane&31)][j, k=c*16+
//   (lane>>5)*8+i] (0 if k>=Fi): W0 (KC16=3, /3 index), W1/W2 (KC16=8).
__global__ void prep_w_kernel(const float* __restrict__ W0s,
                              unsigned short* __restrict__ Wf0,
                              const float* __restrict__ W1s,
                              unsigned short* __restrict__ Wf1,
                              const float* __restrict__ W2s,
                              unsigned short* __restrict__ Wf2) {
  const int t = threadIdx.x;
  int blk = blockIdx.x;
  constexpr int TW0  = NB_F0 * 4 * 3 * 512;   // KC16=3
  constexpr int TW12 = NB_F0 * 4 * 8 * 512;   // KC16=8
  constexpr int NB0  = TW0 / 256;
  constexpr int NB12 = TW12 / 256;
  if (blk < NB0) {
    const int idx  = blk * 256 + t;
    const int i    = idx & 7;
    const int lane = (idx >> 3) & 63;
    const int rest = idx >> 9;
    const int c    = rest % 3;
    const int jt   = rest / 3;
    const int tt   = jt & 3;
    const int j    = jt >> 2;
    const int h = tt * 32 + (lane & 31);
    const int k = c * 16 + ((lane >> 5) << 3) + i;
    unsigned short v = 0;
    if (k < NB_F0)
      v = rne_bf16(W0s[(size_t)h * (NB_F0 * NB_F0) + j * NB_F0 + k]);
    Wf0[idx] = v;
    return;
  }
  blk -= NB0;
  const float* Wsrc; unsigned short* Wdst; int idx;
  if (blk < NB12) { Wsrc = W1s; Wdst = Wf1; idx = blk * 256 + t; }
  else            { Wsrc = W2s; Wdst = Wf2; idx = (blk - NB12) * 256 + t; }
  const int i    = idx & 7;
  const int lane = (idx >> 3) & 63;
  const int c    = (idx >> 9) & 7;
  const int jt   = idx >> 12;
  const int tt   = jt & 3;
  const int j    = jt >> 2;
  const int h = tt * 32 + (lane & 31);
  const int k = c * 16 + ((lane >> 5) << 3) + i;
  Wdst[idx] = rne_bf16(Wsrc[(size_t)h * (NB_F0 * 128) + j * 128 + k]);
}

__global__ __launch_bounds__(256, 1) void cin_fused(
    const unsigned short* __restrict__ Wf0,
    const unsigned short* __restrict__ Wf1,
    const unsigned short* __restrict__ Wf2,
    const float* __restrict__ X0g,           // [B][39][16] f32 (raw input)
    const float* __restrict__ bias0,
    const float* __restrict__ bias1,
    const float* __restrict__ bias2,
    float* __restrict__ outp)                // [B][384]
{
  __shared__ __attribute__((aligned(16))) float x0f[4 * NB_F0 * 16];
  __shared__ __attribute__((aligned(16))) unsigned short X0s[4 * 16 * X0ROW];
  __shared__ __attribute__((aligned(16))) unsigned short Xa[4 * 16 * XROW];
  __shared__ __attribute__((aligned(16))) unsigned short Xb[4 * 16 * XROW];

  const int tid  = threadIdx.x;
  const int lane = tid & 63;
  const int wv   = tid >> 6;        // h-tile: h = wv*32 + col
  const int L    = lane >> 5;       // k-half selector within a 16-chunk
  const int col  = lane & 31;       // A row m / B col
  const int bblk = blockIdx.x * 4;  // 4 b per block

  // ---- in-kernel X0 staging (one-time; data has zero cross-block reuse) ----
  {
    const float* src = X0g + (size_t)bblk * (NB_F0 * 16);
    // (1) x0f[bl][j][pos] = X0g[b][j][dp(pos)] (d-permuted factors, f32).
    //     dp swaps bits 2,3 so a lane's 8 factors for MFMA regs r=0..7
    //     (d=(r&3)+8*((r>>2)&1)+4L) are one contiguous 32B run.
    for (int idx = tid; idx < 4 * NB_F0 * 16; idx += 256) {
      const int pos = idx & 15;
      const int dp =
          (pos & 3) | (((pos >> 3) & 1) << 2) | (((pos >> 2) & 1) << 3);
      x0f[idx] = src[(idx & ~15) + dp];   // same j, permuted d: 64B-line local
    }
    // (2) X0s[bl][d][k] = bf16(X0g[b][k][d]), k<39; zero-pad k in [39,48).
    //     L0 A-fragment source (transpose), rows padded to 56 shorts.
    for (int idx = tid; idx < 4 * 16 * 48; idx += 256) {
      const int bl = idx / 768;
      const int rem = idx - bl * 768;
      const int d = rem / 48;
      const int k = rem - d * 48;
      unsigned short v = 0;
      if (k < NB_F0) v = rne_bf16(src[bl * (NB_F0 * 16) + k * 16 + d]);
      X0s[bl * (16 * X0ROW) + d * X0ROW + k] = v;
    }
  }
  __syncthreads();   // publish x0f + X0s

  const int x0base = L * 8;   // all waves share the block's 4 b (broadcast)

  // One CIN layer. KC16 = K-chunks (3 for L0's 48-pad, 8 for Fi=128);
  // AST = Xi A-fragment row stride in shorts (X0ROW LDS L0, XROW LDS L1/L2).
  auto layer = [&](auto kc, auto ast, const unsigned short* __restrict__ Wl,
                   const unsigned short* af_base, const float* __restrict__ bv,
                   float* __restrict__ op, unsigned short* xn) {
    constexpr int KC16 = decltype(kc)::value;
    constexpr int AST  = decltype(ast)::value;

    // ---- Xi A-fragments: chain P covers b_local = 2P + (col>>4) ----
    s16x8 af[2][KC16];
#pragma unroll
    for (int P = 0; P < 2; ++P) {
      const unsigned short* base = af_base +
          (size_t)(2 * P + (col >> 4)) * (16 * AST) + (col & 15) * AST + L * 8;
#pragma unroll
      for (int c = 0; c < KC16; ++c) af[P][c] = *(const s16x8*)(base + c * 16);
    }

    f32x16 Xacc[2], kZero;
#pragma unroll
    for (int r = 0; r < 16; ++r) kZero[r] = 0.f;
#pragma unroll
    for (int P = 0; P < 2; ++P) Xacc[P] = kZero;

    // ---- W fragments straight from global (L2-hot) into registers ----
    const s16x8* __restrict__ W8 = (const s16x8*)Wl;
    auto wload = [&](int j, s16x8 (&w)[KC16]) {
      const s16x8* p = W8 + ((size_t)(j * 4 + wv) * KC16) * 64 + lane;
#pragma unroll
      for (int c = 0; c < KC16; ++c) w[c] = p[c * 64];
    };

    auto compute = [&](int s, const s16x8 (&w)[KC16]) {
#pragma unroll
      for (int P = 0; P < 2; ++P) {
        __builtin_amdgcn_s_setprio(1);          // T5: favor MFMA cluster
        f32x16 y = __builtin_amdgcn_mfma_f32_32x32x16_bf16(af[P][0], w[0],
                                                           kZero, 0, 0, 0);
#pragma unroll
        for (int c = 1; c < KC16; ++c)
          y = __builtin_amdgcn_mfma_f32_32x32x16_bf16(af[P][c], w[c], y,
                                                      0, 0, 0);
        __builtin_amdgcn_s_setprio(0);
        // x0 scale: regs 0-7 <- b'=2P (this lane's L 8-run), 8-15 <- 2P+1.
        // f32 factors: broadcast ds_read_b128 x4, zero unpack VALU.
        const float* xr0 = &x0f[x0base + (2 * P + 0) * (NB_F0 * 16) + s * 16];
        const float* xr1 = &x0f[x0base + (2 * P + 1) * (NB_F0 * 16) + s * 16];
        const f32x4 a0 = *(const f32x4*)(xr0);
        const f32x4 a1 = *(const f32x4*)(xr0 + 4);
        const f32x4 a2 = *(const f32x4*)(xr1);
        const f32x4 a3 = *(const f32x4*)(xr1 + 4);
        f32x16 xsc;
#pragma unroll
        for (int i = 0; i < 4; ++i) {
          xsc[i]      = a0[i];
          xsc[4 + i]  = a1[i];
          xsc[8 + i]  = a2[i];
          xsc[12 + i] = a3[i];
        }
        Xacc[P] = __builtin_elementwise_fma(xsc, y, Xacc[P]);
      }
    };

    // ---- barrier-free main loop: W reg ping-pong, 1-stage prefetch ----
    s16x8 wA[KC16], wB[KC16];
    wload(0, wA);
    wload(1, wB);
    int s = 0;
    for (; s + 2 <= NB_F0; s += 2) {
      compute(s, wA);
      wload(s + 2 < NB_F0 ? s + 2 : 0, wA);   // reissue post-use (reg WAR ok)
      compute(s + 1, wB);
      if (s + 3 < NB_F0) wload(s + 3, wB);
    }
    if (s < NB_F0) compute(s, wA);   // odd tail (S=39)

    // ---- epilogue: sums to global; Xn to LDS in A-fragment layout ----
    const float bias_v = bv[wv * 32 + col];
#pragma unroll
    for (int P = 0; P < 2; ++P) {
#pragma unroll
      for (int bh = 0; bh < 2; ++bh) {
        const int bl = 2 * P + bh;
        float v[8];
#pragma unroll
        for (int m = 0; m < 8; ++m) v[m] = Xacc[P][bh * 8 + m] + bias_v;
        if (xn) {
#pragma unroll
          for (int m = 0; m < 8; ++m) {
            const int d = (m & 3) + 8 * ((m >> 2) & 1) + 4 * L;
            xn[(bl * 16 + d) * XROW + wv * 32 + col] = rne_bf16(v[m]);
          }
        }
        float tot = ((v[0] + v[1]) + (v[2] + v[3])) +
                    ((v[4] + v[5]) + (v[6] + v[7]));
        tot += __shfl_xor(tot, 32);
        if (lane < 32) op[(size_t)(bblk + bl) * 384 + wv * 32 + lane] = tot;
      }
    }
  };

  layer(IC<3>{}, IC<X0ROW>{}, Wf0, X0s, bias0, outp + 0, Xa);
  __syncthreads();   // publish X1 before L1 af reads
  layer(IC<8>{}, IC<XROW>{}, Wf1, Xa, bias1, outp + 128, Xb);
  __syncthreads();   // publish X2 before L2 af reads
  layer(IC<8>{}, IC<XROW>{}, Wf2, Xb, bias2, outp + 256,
        (unsigned short*)nullptr);
}

extern "C" void kernel_launch(void* const* d_in, const int* in_sizes, int n_in,
                              void* d_out, int out_size, void* d_ws, size_t ws_size,
                              hipStream_t stream) {
  (void)in_sizes; (void)n_in; (void)out_size; (void)ws_size;
  const float* X0g = (const float*)d_in[0];
  const float* W0  = (const float*)d_in[1];
  const float* b0  = (const float*)d_in[2];
  const float* W1  = (const float*)d_in[3];
  const float* b1  = (const float*)d_in[4];
  const float* W2  = (const float*)d_in[5];
  const float* b2  = (const float*)d_in[6];
  float* out = (float*)d_out;

  char* p = (char*)d_ws;
  unsigned short* Wf0 = (unsigned short*)p; p += (size_t)NB_F0 * 4 * 3 * 512 * 2;
  unsigned short* Wf1 = (unsigned short*)p; p += (size_t)NB_F0 * 4 * 8 * 512 * 2;
  unsigned short* Wf2 = (unsigned short*)p; p += (size_t)NB_F0 * 4 * 8 * 512 * 2;

  constexpr int TW0  = NB_F0 * 4 * 3 * 512;
  constexpr int TW12 = NB_F0 * 4 * 8 * 512;
  const int prep_blocks = TW0 / 256 + 2 * (TW12 / 256);
  hipLaunchKernelGGL(prep_w_kernel, dim3(prep_blocks), dim3(256), 0, stream,
                     W0, Wf0, W1, Wf1, W2, Wf2);

  hipLaunchKernelGGL(cin_fused, dim3(NB_B / 4), dim3(256), 0, stream,
                     Wf0, Wf1, Wf2, X0g, b0, b1, b2, out);
}